// Round 13
// baseline (164.151 us; speedup 1.0000x reference)
//
#include <hip/hip_runtime.h>
#include <cstdint>
#include <cstddef>

typedef unsigned short u16;
typedef __attribute__((ext_vector_type(8))) short s16x8;
typedef __attribute__((ext_vector_type(8))) u16 u16x8;
typedef __attribute__((ext_vector_type(4))) float f32x4;

#define DEV static __device__ __forceinline__
#define GPTR(p) (const __attribute__((address_space(1))) void*)(p)
#define LPTR(p) (__attribute__((address_space(3))) void*)(p)
#define SCHEDB __builtin_amdgcn_sched_barrier(0)
#define BAR __builtin_amdgcn_s_barrier()
#define SETP1 __builtin_amdgcn_s_setprio(1)
#define SETP0 __builtin_amdgcn_s_setprio(0)

DEV float b2f(u16 u) { union { unsigned i; float f; } c; c.i = ((unsigned)u) << 16; return c.f; }
DEV u16 f2b(float f) {
  union { float f; unsigned i; } c; c.f = f;
  unsigned r = (c.i + 0x7fffu + ((c.i >> 16) & 1u)) >> 16;
  return (u16)r;
}
DEV float sigm(float x) { return 1.0f / (1.0f + __expf(-x)); }

// ---------------------------------------------------------------------------
// Pack gate weights (f32 in) into concatenated bf16 [N,1536]:
//   WZR rows 0..1023    = [W_xz | W_hz | W_mz]
//   WZR rows 1024..2047 = [W_xr | W_hr | W_mr]
//   WH  rows 0..1023    = [W_xh | W_hh | W_mh]
// plus bf16 copy of W_gamma_h -> WGH [1024,256].
// ---------------------------------------------------------------------------
__global__ __launch_bounds__(256) void pack_w(
    const float* __restrict__ Wxz, const float* __restrict__ Whz, const float* __restrict__ Wmz,
    const float* __restrict__ Wxr, const float* __restrict__ Whr, const float* __restrict__ Wmr,
    const float* __restrict__ Wxh, const float* __restrict__ Whh, const float* __restrict__ Wmh,
    const float* __restrict__ Wgh,
    u16* __restrict__ WZR, u16* __restrict__ WH, u16* __restrict__ WGH)
{
  int t = blockIdx.x * 256 + threadIdx.x;
  const float* src;
  u16* dst;
  if (t < 589824) {
    int row = t / 192;
    int col = (t % 192) * 8;
    int rr = row & 1023;
    const float *wx, *wh, *wm;
    if (row < 1024)      { wx = Wxz; wh = Whz; wm = Wmz; }
    else if (row < 2048) { wx = Wxr; wh = Whr; wm = Wmr; }
    else                 { wx = Wxh; wh = Whh; wm = Wmh; }
    if (col < 256)       src = wx + rr * 256 + col;
    else if (col < 1280) src = wh + (size_t)rr * 1024 + (col - 256);
    else                 src = wm + rr * 256 + (col - 1280);
    dst = (row < 2048) ? (WZR + (size_t)row * 1536 + col)
                       : (WH + (size_t)(row - 2048) * 1536 + col);
  } else {
    int t2 = t - 589824;
    src = Wgh + t2 * 8;
    dst = WGH + t2 * 8;
  }
  f32x4 a = *(const f32x4*)src;
  f32x4 b = *(const f32x4*)(src + 4);
  u16x8 v;
#pragma unroll
  for (int j = 0; j < 4; ++j) { v[j] = f2b(a[j]); v[j + 4] = f2b(b[j]); }
  *(u16x8*)dst = v;
}

// ---------------------------------------------------------------------------
// Elementwise over [B,D]: gamma_x, imputation, x_hat -> X1/X2 cols 0..255 and
// 1280..1535 (m), bf16 delta copy, f32 x_last_obs_new.
// ---------------------------------------------------------------------------
__global__ __launch_bounds__(256) void elem_k(
    const float* __restrict__ x, const float* __restrict__ m, const float* __restrict__ delta,
    const float* __restrict__ xlo, const float* __restrict__ x_mean,
    const float* __restrict__ Wgx, const float* __restrict__ bgx,
    u16* __restrict__ X1, u16* __restrict__ X2, u16* __restrict__ Dbf,
    float* __restrict__ out_xlo)
{
  int t = blockIdx.x * 256 + threadIdx.x;
  int row = t >> 5;
  int col = (t & 31) * 8;
  size_t base = (size_t)row * 256 + col;
  u16x8 vxhat, vm16, vd16;
  f32x4 vlnew[2];
#pragma unroll
  for (int half = 0; half < 2; ++half) {
    f32x4 vx = *(const f32x4*)(x + base + half * 4);
    f32x4 vm = *(const f32x4*)(m + base + half * 4);
    f32x4 vd = *(const f32x4*)(delta + base + half * 4);
    f32x4 vl = *(const f32x4*)(xlo + base + half * 4);
    f32x4 vmean = *(const f32x4*)(x_mean + col + half * 4);
    f32x4 vwg = *(const f32x4*)(Wgx + col + half * 4);
    f32x4 vbg = *(const f32x4*)(bgx + col + half * 4);
#pragma unroll
    for (int j = 0; j < 4; ++j) {
      float mf = vm[j];
      float lnew = (mf > 0.5f) ? vx[j] : vl[j];
      vlnew[half][j] = lnew;
      float gx = __expf(-fmaxf(vd[j] * vwg[j] + vbg[j], 0.0f));
      float ximp = gx * lnew + (1.0f - gx) * vmean[j];
      float xhat = mf * vx[j] + (1.0f - mf) * ximp;
      vxhat[half * 4 + j] = f2b(xhat);
      vm16[half * 4 + j] = f2b(mf);
      vd16[half * 4 + j] = f2b(vd[j]);
    }
  }
  size_t r1536 = (size_t)row * 1536;
  *(u16x8*)(X1 + r1536 + col) = vxhat;
  *(u16x8*)(X2 + r1536 + col) = vxhat;
  *(u16x8*)(X1 + r1536 + 1280 + col) = vm16;
  *(u16x8*)(X2 + r1536 + 1280 + col) = vm16;
  *(u16x8*)(Dbf + base) = vd16;
  *(f32x4*)(out_xlo + base) = vlnew[0];
  *(f32x4*)(out_xlo + base + 4) = vlnew[1];
}

// ---------------------------------------------------------------------------
// GEMM-B: 256x256-tile (r11 geometry) + 1-PHASE FRAG READ-AHEAD (new).
// 8 waves (2Mx4N), per-wave 128x64 (acc 8x4). LDS 128KB: As/Bs[buf*2+kh]
// [256x32] slots, 0-conflict swizzle (verified r2-r12).
// Sub-phase u body: { issue ds_reads for phase u+1's frags (their slot was
//   published >=1 BAR ago) ; stage one 2-load unit for tile t+1 ; MFMA on
//   frags read during phase u-1 (NO lgkm dependency in this phase -- the
//   compiler's counted lgkm lets reads service UNDER the MFMA cluster) ;
//   SCHEDB ; [vmcnt(2) at sub0/sub2] ; BAR }.
// Ledger (induction; outstanding loads entering sub0(t) = 4 = (t,k1)):
//   sub0 +SA(t+1,k0)->6, vmcnt(2)->2 drains (t,k1): published BAR(sub0),
//        read-ahead at sub1 ✓
//   sub1 +SB(t+1,k0)->4
//   sub2 +SA(t+1,k1)->6, vmcnt(2)->2 drains (t+1,k0): published BAR(sub2),
//        read-ahead at sub3 ✓
//   sub3 +SB(t+1,k1)->4 -> entering sub0(t+1) = 4 ✓
// Read-retire vs restage: frags read at phase u retire at the compiler lgkm
//   before their MFMA (phase u+1); any wave reaching that slot's restage
//   (>=3 phases later) has passed >=2 intervening BARs which the slow wave
//   can only release after its consuming MFMA -> no WAR race.
// Prologue: 4 units, vmcnt(4) (drains k0), BAR, read sub0 frags.
// Tail: t=NT-1 stages its own data (ko=0) into the dead buffer; final
//   vmcnt(0). Frag sets afA/afB (M-halves) and bf0/bf1 (k-halves) are
//   statically named (rule #20).
// Epilogue EPI1: cols<1024: z=sigmoid -> Z ; cols>=1024: r*hdec -> X2.
// ---------------------------------------------------------------------------
__global__ __launch_bounds__(512, 2) void gemm_b256(
    const u16* __restrict__ A, const u16* __restrict__ W,
    const float* __restrict__ bz, const float* __restrict__ br,
    const u16* __restrict__ X1h, u16* __restrict__ Z, u16* __restrict__ X2)
{
  constexpr int K = 1536, NT = 24;
  __shared__ alignas(16) u16 As[4][8192];   // [buf*2+kh][256 rows x 32 k]
  __shared__ alignas(16) u16 Bs[4][8192];

  const int tid = threadIdx.x, lane = tid & 63, wave = tid >> 6;
  const int wr = wave >> 2, wc = wave & 3;        // 2M x 4N
  const int d = blockIdx.x;                       // nwg = 256
  const int L = (d & 7) * 32 + (d >> 3);          // bijective XCD map
  const int brow = (L >> 3) * 256, bcol = (L & 7) * 256;
  const int lr = lane & 15, g4 = lane >> 4;
  const int rc = (g4 ^ ((lr >> 1) & 3)) * 8;      // swizzled read chunk
  const int srow = tid >> 2;                      // staging row 0..127
  const int scs = ((tid & 3) ^ ((srow >> 1) & 3)) * 8;

  f32x4 acc[8][4];
#pragma unroll
  for (int i = 0; i < 8; ++i)
#pragma unroll
    for (int j = 0; j < 4; ++j) { f32x4 z0 = {0.f, 0.f, 0.f, 0.f}; acc[i][j] = z0; }

  const u16* aP = A + (size_t)(brow + srow) * K + scs;
  const u16* aQ = aP + (size_t)128 * K;           // rows 128..255
  const u16* bP = W + (size_t)(bcol + srow) * K + scs;
  const u16* bQ = bP + (size_t)128 * K;
  u16* dA = &As[0][0] + tid * 8;                  // lane-linear glds dest
  u16* dB = &Bs[0][0] + tid * 8;
  const u16* rA = &As[0][0] + lr * 32 + rc;
  const u16* rB = &Bs[0][0] + lr * 32 + rc;

  auto SA = [&](int so, int ko) {                 // one A stage unit: 2 loads
    __builtin_amdgcn_global_load_lds(GPTR(aP + ko), LPTR(dA + so), 16, 0, 0);
    __builtin_amdgcn_global_load_lds(GPTR(aQ + ko), LPTR(dA + so + 4096), 16, 0, 0);
  };
  auto SB = [&](int so, int ko) {                 // one B stage unit: 2 loads
    __builtin_amdgcn_global_load_lds(GPTR(bP + ko), LPTR(dB + so), 16, 0, 0);
    __builtin_amdgcn_global_load_lds(GPTR(bQ + ko), LPTR(dB + so + 4096), 16, 0, 0);
  };

  s16x8 afA[4], afB[4], bf0[4], bf1[4];           // static frag sets
  auto RDA = [&](s16x8* dst, int base, int rh) {  // 4 A frags (one M-half)
#pragma unroll
    for (int i = 0; i < 4; ++i)
      dst[i] = *(const s16x8*)(rA + base + (wr * 128 + rh + i * 16) * 32);
  };
  auto RDB = [&](s16x8* dst, int base) {          // 4 B frags
#pragma unroll
    for (int j = 0; j < 4; ++j)
      dst[j] = *(const s16x8*)(rB + base + (wc * 64 + j * 16) * 32);
  };
  auto MM = [&](s16x8* a, s16x8* b, int half) {
    SETP1;
#pragma unroll
    for (int i = 0; i < 4; ++i)
#pragma unroll
      for (int j = 0; j < 4; ++j)
        acc[half * 4 + i][j] = __builtin_amdgcn_mfma_f32_16x16x32_bf16(
            a[i], b[j], acc[half * 4 + i][j], 0, 0, 0);
    SETP0;
  };

  // prologue: stage tile0's 4 units; drain k0; publish; read sub0's frags
  SA(0, 0);     SB(0, 0);
  SA(8192, 32); SB(8192, 32);
  asm volatile("s_waitcnt vmcnt(4)" ::: "memory");
  BAR;
  RDB(bf0, 0); RDA(afA, 0, 0);

  for (int t = 0; t < NT; ++t) {
    const int ro = (t & 1) << 14;                 // this tile's buf base
    const int so = ro ^ 16384;                    // stage target (other buf)
    const int ko = (t + 1 < NT) ? 64 : 0;         // tail: dummy into dead buf
    // ---- sub0: MFMA(afA,bf0) | read-ahead afB(kh0,r64) | SA(t+1,k0) ----
    RDA(afB, ro, 64);
    SA(so, ko);
    MM(afA, bf0, 0);
    SCHEDB;
    asm volatile("s_waitcnt vmcnt(2)" ::: "memory");
    BAR;
    // ---- sub1: MFMA(afB,bf0) | read-ahead bf1+afA(kh1,r0) | SB(t+1,k0) --
    RDB(bf1, ro + 8192); RDA(afA, ro + 8192, 0);
    SB(so, ko);
    MM(afB, bf0, 1);
    SCHEDB;
    BAR;
    // ---- sub2: MFMA(afA,bf1) | read-ahead afB(kh1,r64) | SA(t+1,k1) ----
    RDA(afB, ro + 8192, 64);
    SA(so + 8192, ko + 32);
    MM(afA, bf1, 0);
    SCHEDB;
    asm volatile("s_waitcnt vmcnt(2)" ::: "memory");
    BAR;
    // ---- sub3: MFMA(afB,bf1) | read-ahead next tile's bf0+afA | SB ------
    if (t + 1 < NT) { RDB(bf0, so); RDA(afA, so, 0); }
    SB(so + 8192, ko + 32);
    MM(afB, bf1, 1);
    SCHEDB;
    BAR;
    aP += 64; aQ += 64; bP += 64; bQ += 64;
  }
  asm volatile("s_waitcnt vmcnt(0)" ::: "memory");  // drain dummy stages

  // epilogue: C/D layout col=lane&15, row=(lane>>4)*4+q  [verified m89/m91]
  const int row0 = brow + wr * 128 + g4 * 4;
  const int col0 = bcol + wc * 64 + lr;
#pragma unroll
  for (int i = 0; i < 8; ++i) {
#pragma unroll
    for (int j = 0; j < 4; ++j) {
      int c_ = col0 + j * 16;
#pragma unroll
      for (int qq = 0; qq < 4; ++qq) {
        int r_ = row0 + i * 16 + qq;
        float v = acc[i][j][qq];
        if (c_ < 1024) {
          Z[(size_t)r_ * 1024 + c_] = f2b(sigm(v + bz[c_]));
        } else {
          int jc = c_ - 1024;
          float rg = sigm(v + br[jc]);
          float hd = b2f(X1h[(size_t)r_ * 1536 + 256 + jc]);
          X2[(size_t)r_ * 1536 + 256 + jc] = f2b(rg * hd);
        }
      }
    }
  }
}

// ---------------------------------------------------------------------------
// GEMM A/C (r7 kernel, unchanged): 128x128-tile, 8 waves x 512thr, 2 blk/CU,
// per-wave 64x32, 4-slot ring, counted vmcnt(2). Known-good controls.
// EPI 0: h_decayed = exp(-relu(.+bgh)) * h      -> X1 cols 256..1279 (bf16)
// EPI 2: h_new = (1-z)*hdec + z*tanh(.+bmh)     -> d_out (f32); A = X2
// ---------------------------------------------------------------------------
template<int EPI, int GXL>
__global__ __launch_bounds__(512, 4) void gemm_bt(
    const u16* __restrict__ A, int K, const u16* __restrict__ W,
    const float* __restrict__ bias0, const float* __restrict__ bias1,
    const float* __restrict__ auxf,  // EPI0: h (f32)
    const u16* __restrict__ auxb,    // EPI2: X1 (hdec source, bf16)
    const u16* __restrict__ aux2b,   // EPI2: Z (bf16)
    u16* __restrict__ out0b,         // EPI0: X1
    float* __restrict__ outf)        // EPI2: d_out h_new
{
  constexpr int GX = 1 << GXL;
  constexpr int SL = 128 * 32;
  __shared__ alignas(16) u16 As[4][SL];
  __shared__ alignas(16) u16 Bs[4][SL];

  const int tid = threadIdx.x;
  const int lane = tid & 63;
  const int wave = tid >> 6;
  const int wr = wave >> 2, wc = wave & 3;

  const int d = blockIdx.x;
  const int q = (int)gridDim.x >> 3;
  const int L = (d & 7) * q + (d >> 3);
  const int brow = (L >> GXL) * 128;
  const int bcol = (L & (GX - 1)) * 128;
  const int NT = K / 64;

  const int lr = lane & 15, g4 = lane >> 4;
  const int rc = (g4 ^ ((lr >> 1) & 3)) * 8;
  const int srow = lane >> 2;
  const int scs = ((lane & 3) ^ ((srow >> 1) & 3)) * 8;

  f32x4 acc[4][2];
#pragma unroll
  for (int i = 0; i < 4; ++i)
#pragma unroll
    for (int j = 0; j < 2; ++j) { f32x4 z0 = {0.f, 0.f, 0.f, 0.f}; acc[i][j] = z0; }

  const u16* aP = A + (size_t)(brow + wave * 16 + srow) * K + scs;
  const u16* bP = W + (size_t)(bcol + wave * 16 + srow) * K + scs;
  u16* ldsA = &As[0][0] + wave * 512;
  u16* ldsB = &Bs[0][0] + wave * 512;
  const u16* rdA = &As[0][0] + (wr * 64 + lr) * 32 + rc;
  const u16* rdB = &Bs[0][0] + (wc * 32 + lr) * 32 + rc;

  auto STAGE = [&](int slot, int koff) {
    __builtin_amdgcn_global_load_lds(GPTR(aP + koff), LPTR(ldsA + slot * SL), 16, 0, 0);
    __builtin_amdgcn_global_load_lds(GPTR(bP + koff), LPTR(ldsB + slot * SL), 16, 0, 0);
  };

  auto PHASE = [&](int slotR, int slotS, int koff, int stg, int vm) {
    s16x8 af[4], bf[2];
    const u16* pA = rdA + slotR * SL;
    const u16* pB = rdB + slotR * SL;
#pragma unroll
    for (int i = 0; i < 4; ++i) af[i] = *(const s16x8*)(pA + i * 512);
#pragma unroll
    for (int j = 0; j < 2; ++j) bf[j] = *(const s16x8*)(pB + j * 512);
    if (stg) STAGE(slotS, koff);
    SCHEDB;
    if (vm == 2) asm volatile("s_waitcnt vmcnt(2)" ::: "memory");
    else if (vm == 0) asm volatile("s_waitcnt vmcnt(0)" ::: "memory");
    BAR;
    asm volatile("s_waitcnt lgkmcnt(0)" ::: "memory");
    SCHEDB;
    SETP1;
#pragma unroll
    for (int i = 0; i < 4; ++i)
#pragma unroll
      for (int j = 0; j < 2; ++j)
        acc[i][j] = __builtin_amdgcn_mfma_f32_16x16x32_bf16(af[i], bf[j], acc[i][j], 0, 0, 0);
    SETP0;
  };

  STAGE(0, 0);
  STAGE(1, 32);
  asm volatile("s_waitcnt vmcnt(2)" ::: "memory");
  BAR;

  for (int kt = 0; kt < NT - 2; kt += 2) {
    PHASE(0, 2, 64, 1, 2);
    PHASE(1, 3, 96, 1, 2);
    PHASE(2, 0, 128, 1, 2);
    PHASE(3, 1, 160, 1, 2);
    aP += 128; bP += 128;
  }
  PHASE(0, 2, 64, 1, 2);
  PHASE(1, 3, 96, 1, 2);
  PHASE(2, 0, 0, 0, 0);
  PHASE(3, 0, 0, 0, -1);

  const int row0 = brow + wr * 64 + g4 * 4;
  const int col0 = bcol + wc * 32 + lr;
#pragma unroll
  for (int i = 0; i < 4; ++i) {
#pragma unroll
    for (int j = 0; j < 2; ++j) {
      int c_ = col0 + j * 16;
#pragma unroll
      for (int qq = 0; qq < 4; ++qq) {
        int r_ = row0 + i * 16 + qq;
        float v = acc[i][j][qq];
        if constexpr (EPI == 0) {
          float p = v + bias0[c_];
          float gh = __expf(-fmaxf(p, 0.0f));
          float hd = gh * auxf[(size_t)r_ * 1024 + c_];
          out0b[(size_t)r_ * 1536 + 256 + c_] = f2b(hd);
        } else {
          float ht = tanhf(v + bias0[c_]);
          float zz = b2f(aux2b[(size_t)r_ * 1024 + c_]);
          float hd = b2f(auxb[(size_t)r_ * 1536 + 256 + c_]);
          outf[(size_t)r_ * 1024 + c_] = (1.0f - zz) * hd + zz * ht;
        }
      }
    }
  }
}

// ---------------------------------------------------------------------------
extern "C" void kernel_launch(void* const* d_in, const int* in_sizes, int n_in,
                              void* d_out, int out_size, void* d_ws, size_t ws_size,
                              hipStream_t stream)
{
  const float* x     = (const float*)d_in[0];
  const float* m     = (const float*)d_in[1];
  const float* delta = (const float*)d_in[2];
  const float* h     = (const float*)d_in[3];
  const float* xlo   = (const float*)d_in[4];
  const float* xmean = (const float*)d_in[5];
  const float* Wgx   = (const float*)d_in[6];
  const float* bgx   = (const float*)d_in[7];
  const float* Wgh   = (const float*)d_in[8];
  const float* bgh   = (const float*)d_in[9];
  const float* Wxz   = (const float*)d_in[10];
  const float* Whz   = (const float*)d_in[11];
  const float* Wmz   = (const float*)d_in[12];
  const float* bmz   = (const float*)d_in[13];
  const float* Wxr   = (const float*)d_in[14];
  const float* Whr   = (const float*)d_in[15];
  const float* Wmr   = (const float*)d_in[16];
  const float* bmr   = (const float*)d_in[17];
  const float* Wxh   = (const float*)d_in[18];
  const float* Whh   = (const float*)d_in[19];
  const float* Wmh   = (const float*)d_in[20];
  const float* bmh   = (const float*)d_in[21];

  // workspace (bf16): X1[8192,1536] X2[8192,1536] Z[8192,1024]
  //   WZR[2048,1536] WH[1024,1536] Dbf[8192,256] WGH[1024,256]  ~81.3MB
  u16* X1  = (u16*)d_ws;
  u16* X2  = X1 + (size_t)8192 * 1536;
  u16* Z   = X2 + (size_t)8192 * 1536;
  u16* WZR = Z  + (size_t)8192 * 1024;
  u16* WH  = WZR + (size_t)2048 * 1536;
  u16* Dbf = WH + (size_t)1024 * 1536;
  u16* WGH = Dbf + (size_t)8192 * 256;

  float* out_h   = (float*)d_out;
  float* out_xlo = out_h + (size_t)8192 * 1024;

  pack_w<<<2432, 256, 0, stream>>>(Wxz, Whz, Wmz, Wxr, Whr, Wmr, Wxh, Whh, Wmh, Wgh, WZR, WH, WGH);
  elem_k<<<1024, 256, 0, stream>>>(x, m, delta, xlo, xmean, Wgx, bgx, X1, X2, Dbf, out_xlo);
  // GEMM A: gamma_h -> h_decayed into X1[:,256:1280]   (M=8192,N=1024,K=256)
  gemm_bt<0, 3><<<512, 512, 0, stream>>>(
      Dbf, 256, WGH, bgh, nullptr, h, nullptr, nullptr, X1, nullptr);
  // GEMM B: z -> Z ; r*h_decayed -> X2[:,256:1280]     (M=8192,N=2048,K=1536)
  gemm_b256<<<256, 512, 0, stream>>>(X1, WZR, bmz, bmr, X1, Z, X2);
  // GEMM C: h_tilde + final blend -> h_new (f32)       (M=8192,N=1024,K=1536)
  gemm_bt<2, 3><<<512, 512, 0, stream>>>(
      X2, 1536, WH, bmh, nullptr, nullptr, X1, Z, nullptr, out_h);
}

// Round 14
// 151.937 us; speedup vs baseline: 1.0804x; 1.0804x over previous
//
#include <hip/hip_runtime.h>
#include <cstdint>
#include <cstddef>

typedef unsigned short u16;
typedef __attribute__((ext_vector_type(8))) short s16x8;
typedef __attribute__((ext_vector_type(8))) u16 u16x8;
typedef __attribute__((ext_vector_type(4))) float f32x4;

#define DEV static __device__ __forceinline__
#define GPTR(p) (const __attribute__((address_space(1))) void*)(p)
#define LPTR(p) (__attribute__((address_space(3))) void*)(p)
#define SCHEDB __builtin_amdgcn_sched_barrier(0)
#define BAR __builtin_amdgcn_s_barrier()
#define SETP1 __builtin_amdgcn_s_setprio(1)
#define SETP0 __builtin_amdgcn_s_setprio(0)

DEV float b2f(u16 u) { union { unsigned i; float f; } c; c.i = ((unsigned)u) << 16; return c.f; }
DEV u16 f2b(float f) {
  union { float f; unsigned i; } c; c.f = f;
  unsigned r = (c.i + 0x7fffu + ((c.i >> 16) & 1u)) >> 16;
  return (u16)r;
}
DEV float sigm(float x) { return 1.0f / (1.0f + __expf(-x)); }

// ---------------------------------------------------------------------------
// FUSED prep kernel (saves one launch; overlaps two BW-bound streams).
// Blocks 0..1023: elem_k body — gamma_x, imputation, x_hat -> X1/X2 cols
//   0..255 & 1280..1535 (m), bf16 delta copy, f32 x_last_obs_new.
// Blocks 1024..3455: pack_w body — gate weights f32 -> concatenated bf16:
//   WZR rows 0..1023 = [W_xz|W_hz|W_mz], rows 1024..2047 = [W_xr|W_hr|W_mr],
//   WH rows 0..1023 = [W_xh|W_hh|W_mh]; plus W_gamma_h -> WGH [1024,256].
// ---------------------------------------------------------------------------
__global__ __launch_bounds__(256) void prep_k(
    const float* __restrict__ x, const float* __restrict__ m, const float* __restrict__ delta,
    const float* __restrict__ xlo, const float* __restrict__ x_mean,
    const float* __restrict__ Wgx, const float* __restrict__ bgx,
    const float* __restrict__ Wxz, const float* __restrict__ Whz, const float* __restrict__ Wmz,
    const float* __restrict__ Wxr, const float* __restrict__ Whr, const float* __restrict__ Wmr,
    const float* __restrict__ Wxh, const float* __restrict__ Whh, const float* __restrict__ Wmh,
    const float* __restrict__ Wgh,
    u16* __restrict__ X1, u16* __restrict__ X2, u16* __restrict__ Dbf,
    float* __restrict__ out_xlo,
    u16* __restrict__ WZR, u16* __restrict__ WH, u16* __restrict__ WGH)
{
  if (blockIdx.x < 1024) {
    // ---------------- elem part ----------------
    int t = blockIdx.x * 256 + threadIdx.x;
    int row = t >> 5;
    int col = (t & 31) * 8;
    size_t base = (size_t)row * 256 + col;
    u16x8 vxhat, vm16, vd16;
    f32x4 vlnew[2];
#pragma unroll
    for (int half = 0; half < 2; ++half) {
      f32x4 vx = *(const f32x4*)(x + base + half * 4);
      f32x4 vm = *(const f32x4*)(m + base + half * 4);
      f32x4 vd = *(const f32x4*)(delta + base + half * 4);
      f32x4 vl = *(const f32x4*)(xlo + base + half * 4);
      f32x4 vmean = *(const f32x4*)(x_mean + col + half * 4);
      f32x4 vwg = *(const f32x4*)(Wgx + col + half * 4);
      f32x4 vbg = *(const f32x4*)(bgx + col + half * 4);
#pragma unroll
      for (int j = 0; j < 4; ++j) {
        float mf = vm[j];
        float lnew = (mf > 0.5f) ? vx[j] : vl[j];
        vlnew[half][j] = lnew;
        float gx = __expf(-fmaxf(vd[j] * vwg[j] + vbg[j], 0.0f));
        float ximp = gx * lnew + (1.0f - gx) * vmean[j];
        float xhat = mf * vx[j] + (1.0f - mf) * ximp;
        vxhat[half * 4 + j] = f2b(xhat);
        vm16[half * 4 + j] = f2b(mf);
        vd16[half * 4 + j] = f2b(vd[j]);
      }
    }
    size_t r1536 = (size_t)row * 1536;
    *(u16x8*)(X1 + r1536 + col) = vxhat;
    *(u16x8*)(X2 + r1536 + col) = vxhat;
    *(u16x8*)(X1 + r1536 + 1280 + col) = vm16;
    *(u16x8*)(X2 + r1536 + 1280 + col) = vm16;
    *(u16x8*)(Dbf + base) = vd16;
    *(f32x4*)(out_xlo + base) = vlnew[0];
    *(f32x4*)(out_xlo + base + 4) = vlnew[1];
  } else {
    // ---------------- pack part ----------------
    int t = (blockIdx.x - 1024) * 256 + threadIdx.x;
    const float* src;
    u16* dst;
    if (t < 589824) {
      int row = t / 192;
      int col = (t % 192) * 8;
      int rr = row & 1023;
      const float *wx, *wh, *wm;
      if (row < 1024)      { wx = Wxz; wh = Whz; wm = Wmz; }
      else if (row < 2048) { wx = Wxr; wh = Whr; wm = Wmr; }
      else                 { wx = Wxh; wh = Whh; wm = Wmh; }
      if (col < 256)       src = wx + rr * 256 + col;
      else if (col < 1280) src = wh + (size_t)rr * 1024 + (col - 256);
      else                 src = wm + rr * 256 + (col - 1280);
      dst = (row < 2048) ? (WZR + (size_t)row * 1536 + col)
                         : (WH + (size_t)(row - 2048) * 1536 + col);
    } else {
      int t2 = t - 589824;
      src = Wgh + t2 * 8;
      dst = WGH + t2 * 8;
    }
    f32x4 a = *(const f32x4*)src;
    f32x4 b = *(const f32x4*)(src + 4);
    u16x8 v;
#pragma unroll
    for (int j = 0; j < 4; ++j) { v[j] = f2b(a[j]); v[j + 4] = f2b(b[j]); }
    *(u16x8*)dst = v;
  }
}

// ---------------------------------------------------------------------------
// GEMM-B (r8 kernel, measured 79.3us): 256x128-tile, 8 waves (4Mx2N),
// per-wave 64x64 (acc 4x4), ring-3 of BK=32 k-half slots, 72KB LDS ->
// 2 blocks/CU (4 waves/SIMD in two independent barrier groups).
// Phase u: { ds_read 8 frags (slot u%3) ; STAGE unit u+2 -> slot (u+2)%3
//   (2 A-loads + 1 B-load per thread) ; vmcnt(3)+lgkm0 (PRE-barrier) ;
//   BAR ; 16 MFMA }.
// Race ledger: reads of slot s (phase u) retire at u's lgkm0 PRE-BAR(u);
//   restage of s issued at phase u+1 POST-BAR(u) -> ordered. Unit u+1
//   drained by every wave's vmcnt(3) pre-BAR(u) -> landed before any wave's
//   phase-u+1 reads. Tail: clamped dummy stages keep vmcnt uniform; final
//   vmcnt(0). Full 48-phase unroll: all slot offsets literal.
// Swizzle (0-conflict r2-r12): 16B chunk ^= (row>>1)&3, linear LDS dest +
//   inverse-swizzled global src + swizzled ds_read. XCD-bijective map.
// Epilogue: cols<1024: z=sigmoid -> Z ; cols>=1024: r*hdec -> X2.
// ---------------------------------------------------------------------------
__global__ __launch_bounds__(512, 4) void gemm_b256(
    const u16* __restrict__ A, const u16* __restrict__ W,
    const float* __restrict__ bz, const float* __restrict__ br,
    const u16* __restrict__ X1h, u16* __restrict__ Z, u16* __restrict__ X2)
{
  constexpr int K = 1536, P = 48;
  __shared__ alignas(16) u16 As[3][8192];   // 256 rows x 32 k  (16KB/slot)
  __shared__ alignas(16) u16 Bs[3][4096];   // 128 rows x 32 k  ( 8KB/slot)

  const int tid = threadIdx.x, lane = tid & 63, wave = tid >> 6;
  const int wr = wave >> 1, wc = wave & 1;        // 4M x 2N
  const int d = blockIdx.x;                       // nwg = 512
  const int L = (d & 7) * 64 + (d >> 3);          // bijective XCD map
  const int brow = (L >> 4) * 256, bcol = (L & 15) * 128;
  const int lr = lane & 15, g4 = lane >> 4;
  const int rc = (g4 ^ ((lr >> 1) & 3)) * 8;      // swizzled read chunk
  const int srow = tid >> 2;                      // staging row 0..127
  const int scs = ((tid & 3) ^ ((srow >> 1) & 3)) * 8;

  f32x4 acc[4][4];
#pragma unroll
  for (int i = 0; i < 4; ++i)
#pragma unroll
    for (int j = 0; j < 4; ++j) { f32x4 z0 = {0.f, 0.f, 0.f, 0.f}; acc[i][j] = z0; }

  const u16* aP = A + (size_t)(brow + srow) * K + scs;
  const u16* aQ = aP + (size_t)128 * K;           // rows 128..255
  const u16* bP = W + (size_t)(bcol + srow) * K + scs;
  u16* dA = &As[0][0] + tid * 8;                  // lane-linear glds dest
  u16* dB = &Bs[0][0] + tid * 8;
  const u16* rA = &As[0][0] + (wr * 64 + lr) * 32 + rc;
  const u16* rB = &Bs[0][0] + (wc * 64 + lr) * 32 + rc;

  auto STAGE = [&](int slot, int ko) {
    __builtin_amdgcn_global_load_lds(GPTR(aP + ko), LPTR(dA + slot * 8192), 16, 0, 0);
    __builtin_amdgcn_global_load_lds(GPTR(aQ + ko), LPTR(dA + slot * 8192 + 4096), 16, 0, 0);
    __builtin_amdgcn_global_load_lds(GPTR(bP + ko), LPTR(dB + slot * 4096), 16, 0, 0);
  };

  // prologue: units 0,1 -> slots 0,1; drain unit 0; publish
  STAGE(0, 0);
  STAGE(1, 32);
  asm volatile("s_waitcnt vmcnt(3)" ::: "memory");
  BAR;

#pragma unroll
  for (int u = 0; u < P; ++u) {
    const int sR = u % 3;
    const int sS = (u + 2) % 3;
    const int ko = ((u + 2 < P) ? (u + 2) : (P - 1)) * 32;  // tail: dummy
    s16x8 af[4], bf[4];
#pragma unroll
    for (int i = 0; i < 4; ++i) af[i] = *(const s16x8*)(rA + sR * 8192 + i * 512);
#pragma unroll
    for (int j = 0; j < 4; ++j) bf[j] = *(const s16x8*)(rB + sR * 4096 + j * 512);
    STAGE(sS, ko);
    SCHEDB;
    asm volatile("s_waitcnt vmcnt(3) lgkmcnt(0)" ::: "memory");
    SCHEDB;
    BAR;
    SETP1;
#pragma unroll
    for (int i = 0; i < 4; ++i)
#pragma unroll
      for (int j = 0; j < 4; ++j)
        acc[i][j] = __builtin_amdgcn_mfma_f32_16x16x32_bf16(af[i], bf[j], acc[i][j], 0, 0, 0);
    SETP0;
  }
  asm volatile("s_waitcnt vmcnt(0)" ::: "memory");  // drain dummy stages

  // epilogue: C/D layout col=lane&15, row=(lane>>4)*4+q  [verified m89/m91]
  const int row0 = brow + wr * 64 + g4 * 4;
  const int col0 = bcol + wc * 64 + lr;
#pragma unroll
  for (int i = 0; i < 4; ++i) {
#pragma unroll
    for (int j = 0; j < 4; ++j) {
      int c_ = col0 + j * 16;
#pragma unroll
      for (int qq = 0; qq < 4; ++qq) {
        int r_ = row0 + i * 16 + qq;
        float v = acc[i][j][qq];
        if (c_ < 1024) {
          Z[(size_t)r_ * 1024 + c_] = f2b(sigm(v + bz[c_]));
        } else {
          int jc = c_ - 1024;
          float rg = sigm(v + br[jc]);
          float hd = b2f(X1h[(size_t)r_ * 1536 + 256 + jc]);
          X2[(size_t)r_ * 1536 + 256 + jc] = f2b(rg * hd);
        }
      }
    }
  }
}

// ---------------------------------------------------------------------------
// GEMM A/C (r7 kernel, unchanged): 128x128-tile, 8 waves x 512thr, 2 blk/CU,
// per-wave 64x32, 4-slot ring, counted vmcnt(2). Known-good controls.
// EPI 0: h_decayed = exp(-relu(.+bgh)) * h      -> X1 cols 256..1279 (bf16)
// EPI 2: h_new = (1-z)*hdec + z*tanh(.+bmh)     -> d_out (f32); A = X2
// ---------------------------------------------------------------------------
template<int EPI, int GXL>
__global__ __launch_bounds__(512, 4) void gemm_bt(
    const u16* __restrict__ A, int K, const u16* __restrict__ W,
    const float* __restrict__ bias0, const float* __restrict__ bias1,
    const float* __restrict__ auxf,  // EPI0: h (f32)
    const u16* __restrict__ auxb,    // EPI2: X1 (hdec source, bf16)
    const u16* __restrict__ aux2b,   // EPI2: Z (bf16)
    u16* __restrict__ out0b,         // EPI0: X1
    float* __restrict__ outf)        // EPI2: d_out h_new
{
  constexpr int GX = 1 << GXL;
  constexpr int SL = 128 * 32;
  __shared__ alignas(16) u16 As[4][SL];
  __shared__ alignas(16) u16 Bs[4][SL];

  const int tid = threadIdx.x;
  const int lane = tid & 63;
  const int wave = tid >> 6;
  const int wr = wave >> 2, wc = wave & 3;

  const int d = blockIdx.x;
  const int q = (int)gridDim.x >> 3;
  const int L = (d & 7) * q + (d >> 3);
  const int brow = (L >> GXL) * 128;
  const int bcol = (L & (GX - 1)) * 128;
  const int NT = K / 64;

  const int lr = lane & 15, g4 = lane >> 4;
  const int rc = (g4 ^ ((lr >> 1) & 3)) * 8;
  const int srow = lane >> 2;
  const int scs = ((lane & 3) ^ ((srow >> 1) & 3)) * 8;

  f32x4 acc[4][2];
#pragma unroll
  for (int i = 0; i < 4; ++i)
#pragma unroll
    for (int j = 0; j < 2; ++j) { f32x4 z0 = {0.f, 0.f, 0.f, 0.f}; acc[i][j] = z0; }

  const u16* aP = A + (size_t)(brow + wave * 16 + srow) * K + scs;
  const u16* bP = W + (size_t)(bcol + wave * 16 + srow) * K + scs;
  u16* ldsA = &As[0][0] + wave * 512;
  u16* ldsB = &Bs[0][0] + wave * 512;
  const u16* rdA = &As[0][0] + (wr * 64 + lr) * 32 + rc;
  const u16* rdB = &Bs[0][0] + (wc * 32 + lr) * 32 + rc;

  auto STAGE = [&](int slot, int koff) {
    __builtin_amdgcn_global_load_lds(GPTR(aP + koff), LPTR(ldsA + slot * SL), 16, 0, 0);
    __builtin_amdgcn_global_load_lds(GPTR(bP + koff), LPTR(ldsB + slot * SL), 16, 0, 0);
  };

  auto PHASE = [&](int slotR, int slotS, int koff, int stg, int vm) {
    s16x8 af[4], bf[2];
    const u16* pA = rdA + slotR * SL;
    const u16* pB = rdB + slotR * SL;
#pragma unroll
    for (int i = 0; i < 4; ++i) af[i] = *(const s16x8*)(pA + i * 512);
#pragma unroll
    for (int j = 0; j < 2; ++j) bf[j] = *(const s16x8*)(pB + j * 512);
    if (stg) STAGE(slotS, koff);
    SCHEDB;
    if (vm == 2) asm volatile("s_waitcnt vmcnt(2)" ::: "memory");
    else if (vm == 0) asm volatile("s_waitcnt vmcnt(0)" ::: "memory");
    BAR;
    asm volatile("s_waitcnt lgkmcnt(0)" ::: "memory");
    SCHEDB;
    SETP1;
#pragma unroll
    for (int i = 0; i < 4; ++i)
#pragma unroll
      for (int j = 0; j < 2; ++j)
        acc[i][j] = __builtin_amdgcn_mfma_f32_16x16x32_bf16(af[i], bf[j], acc[i][j], 0, 0, 0);
    SETP0;
  };

  STAGE(0, 0);
  STAGE(1, 32);
  asm volatile("s_waitcnt vmcnt(2)" ::: "memory");
  BAR;

  for (int kt = 0; kt < NT - 2; kt += 2) {
    PHASE(0, 2, 64, 1, 2);
    PHASE(1, 3, 96, 1, 2);
    PHASE(2, 0, 128, 1, 2);
    PHASE(3, 1, 160, 1, 2);
    aP += 128; bP += 128;
  }
  PHASE(0, 2, 64, 1, 2);
  PHASE(1, 3, 96, 1, 2);
  PHASE(2, 0, 0, 0, 0);
  PHASE(3, 0, 0, 0, -1);

  const int row0 = brow + wr * 64 + g4 * 4;
  const int col0 = bcol + wc * 32 + lr;
#pragma unroll
  for (int i = 0; i < 4; ++i) {
#pragma unroll
    for (int j = 0; j < 2; ++j) {
      int c_ = col0 + j * 16;
#pragma unroll
      for (int qq = 0; qq < 4; ++qq) {
        int r_ = row0 + i * 16 + qq;
        float v = acc[i][j][qq];
        if constexpr (EPI == 0) {
          float p = v + bias0[c_];
          float gh = __expf(-fmaxf(p, 0.0f));
          float hd = gh * auxf[(size_t)r_ * 1024 + c_];
          out0b[(size_t)r_ * 1536 + 256 + c_] = f2b(hd);
        } else {
          float ht = tanhf(v + bias0[c_]);
          float zz = b2f(aux2b[(size_t)r_ * 1024 + c_]);
          float hd = b2f(auxb[(size_t)r_ * 1536 + 256 + c_]);
          outf[(size_t)r_ * 1024 + c_] = (1.0f - zz) * hd + zz * ht;
        }
      }
    }
  }
}

// ---------------------------------------------------------------------------
extern "C" void kernel_launch(void* const* d_in, const int* in_sizes, int n_in,
                              void* d_out, int out_size, void* d_ws, size_t ws_size,
                              hipStream_t stream)
{
  const float* x     = (const float*)d_in[0];
  const float* m     = (const float*)d_in[1];
  const float* delta = (const float*)d_in[2];
  const float* h     = (const float*)d_in[3];
  const float* xlo   = (const float*)d_in[4];
  const float* xmean = (const float*)d_in[5];
  const float* Wgx   = (const float*)d_in[6];
  const float* bgx   = (const float*)d_in[7];
  const float* Wgh   = (const float*)d_in[8];
  const float* bgh   = (const float*)d_in[9];
  const float* Wxz   = (const float*)d_in[10];
  const float* Whz   = (const float*)d_in[11];
  const float* Wmz   = (const float*)d_in[12];
  const float* bmz   = (const float*)d_in[13];
  const float* Wxr   = (const float*)d_in[14];
  const float* Whr   = (const float*)d_in[15];
  const float* Wmr   = (const float*)d_in[16];
  const float* bmr   = (const float*)d_in[17];
  const float* Wxh   = (const float*)d_in[18];
  const float* Whh   = (const float*)d_in[19];
  const float* Wmh   = (const float*)d_in[20];
  const float* bmh   = (const float*)d_in[21];

  // workspace (bf16): X1[8192,1536] X2[8192,1536] Z[8192,1024]
  //   WZR[2048,1536] WH[1024,1536] Dbf[8192,256] WGH[1024,256]  ~81.3MB
  u16* X1  = (u16*)d_ws;
  u16* X2  = X1 + (size_t)8192 * 1536;
  u16* Z   = X2 + (size_t)8192 * 1536;
  u16* WZR = Z  + (size_t)8192 * 1024;
  u16* WH  = WZR + (size_t)2048 * 1536;
  u16* Dbf = WH + (size_t)1024 * 1536;
  u16* WGH = Dbf + (size_t)8192 * 256;

  float* out_h   = (float*)d_out;
  float* out_xlo = out_h + (size_t)8192 * 1024;

  // fused elem + pack (blocks 0..1023 elem, 1024..3455 pack)
  prep_k<<<3456, 256, 0, stream>>>(
      x, m, delta, xlo, xmean, Wgx, bgx,
      Wxz, Whz, Wmz, Wxr, Whr, Wmr, Wxh, Whh, Wmh, Wgh,
      X1, X2, Dbf, out_xlo, WZR, WH, WGH);
  // GEMM A: gamma_h -> h_decayed into X1[:,256:1280]   (M=8192,N=1024,K=256)
  gemm_bt<0, 3><<<512, 512, 0, stream>>>(
      Dbf, 256, WGH, bgh, nullptr, h, nullptr, nullptr, X1, nullptr);
  // GEMM B: z -> Z ; r*h_decayed -> X2[:,256:1280]     (M=8192,N=2048,K=1536)
  gemm_b256<<<512, 512, 0, stream>>>(X1, WZR, bmz, bmr, X1, Z, X2);
  // GEMM C: h_tilde + final blend -> h_new (f32)       (M=8192,N=1024,K=1536)
  gemm_bt<2, 3><<<512, 512, 0, stream>>>(
      X2, 1536, WH, bmh, nullptr, nullptr, X1, Z, nullptr, out_h);
}